// Round 4
// baseline (382.231 us; speedup 1.0000x reference)
//
#include <hip/hip_runtime.h>
#include <hip/hip_bf16.h>

// AttnBlock: x[4,512,64,64] fp32. GroupNorm(8) -> qkv 1x1conv -> attn -> proj -> +xn
// Q,K,V,P fp8 e4m3. R9: fattn re-tiled for 2 blocks/CU: j-step 64, 256 thr/4 waves
// (wi x wj = 2x2), Ksm 32KB + Vsm 32KB (2-rows-per-128B-line packing, R2-verified)
// + Pp 4KB = 70KB LDS -> 2 blocks/CU. Two co-resident blocks at independent phases
// overlap softmax-VALU/barrier waits of one with MFMA of the other (m114 mechanism).
// Per step: {syncA (drains K stage) ; stage V_t ; S=QK (8 MFMA, c=512) ; exp2 ->
// P fp8 LDS + rowsum ; syncB (drains V stage, P visible) ; stage K_{t+1} ;
// acc[2][4] += P.V^T (8 MFMA, k=64)}. Epilogue: cross-wave l reduce, H=(PV)/l bf16.

typedef unsigned short u16;
typedef unsigned char u8;
typedef __bf16 bf16x8 __attribute__((ext_vector_type(8)));
typedef float f32x4 __attribute__((ext_vector_type(4)));
typedef float f32x16 __attribute__((ext_vector_type(16)));
typedef int i32x4 __attribute__((ext_vector_type(4)));
typedef int i32x8 __attribute__((ext_vector_type(8)));
typedef unsigned short u16x4 __attribute__((ext_vector_type(4)));

#define CDIM 512
#define NPOS 4096
#define NBATCH 4

__device__ __forceinline__ u16 f2bf(float x) {
  union { float f; unsigned u; } c; c.f = x;
  unsigned u = c.u;
  u += 0x7fffu + ((u >> 16) & 1u);   // round-to-nearest-even
  return (u16)(u >> 16);
}
__device__ __forceinline__ float bf2f(u16 h) {
  union { unsigned u; float f; } c; c.u = ((unsigned)h) << 16;
  return c.f;
}
// pack 4 floats -> 4 fp8 e4m3 bytes
__device__ __forceinline__ unsigned pk4_fp8(float a, float b, float c, float d) {
  unsigned v = __builtin_amdgcn_cvt_pk_fp8_f32(a, b, 0, false);
  v = __builtin_amdgcn_cvt_pk_fp8_f32(c, d, v, true);
  return v;
}

__device__ __forceinline__ void async16(const u16* g, u16* l) {
  __builtin_amdgcn_global_load_lds(
      (const __attribute__((address_space(1))) unsigned int*)g,
      (__attribute__((address_space(3))) unsigned int*)l, 16, 0, 0);
}
__device__ __forceinline__ void async16b(const u8* g, u8* l) {
  __builtin_amdgcn_global_load_lds(
      (const __attribute__((address_space(1))) unsigned int*)g,
      (__attribute__((address_space(3))) unsigned int*)l, 16, 0, 0);
}

__device__ __forceinline__ void drain_barrier() {
  asm volatile("s_waitcnt vmcnt(0)" ::: "memory");
  __builtin_amdgcn_s_barrier();
}

__device__ __forceinline__ float wred_sum(float v) {
#pragma unroll
  for (int o = 32; o > 0; o >>= 1) v += __shfl_xor(v, o, 64);
  return v;
}

// ---------------- GroupNorm stats: 32 (b,g) groups x 8 slices ----------------
__global__ __launch_bounds__(256) void gn_partial(const float* __restrict__ x,
                                                  float* __restrict__ stats) {
  int gidx = blockIdx.x >> 3;
  int slice = blockIdx.x & 7;
  const float4* src = (const float4*)x + (long)gidx * 65536 + (long)slice * 8192;
  float s = 0.f, ss = 0.f;
  for (int i = threadIdx.x; i < 8192; i += 256) {
    float4 v = src[i];
    s  += v.x + v.y + v.z + v.w;
    ss += v.x * v.x + v.y * v.y + v.z * v.z + v.w * v.w;
  }
  s = wred_sum(s); ss = wred_sum(ss);
  __shared__ float r1[4], r2[4];
  int lane = threadIdx.x & 63, wave = threadIdx.x >> 6;
  if (lane == 0) { r1[wave] = s; r2[wave] = ss; }
  __syncthreads();
  if (threadIdx.x == 0) {
    atomicAdd(&stats[gidx * 2 + 0], r1[0] + r1[1] + r1[2] + r1[3]);
    atomicAdd(&stats[gidx * 2 + 1], r2[0] + r2[1] + r2[2] + r2[3]);
  }
}

// ------- normalize + write xnb bf16 [b,c,p] (residual) and xnT bf16 [b,p,c] -------
__global__ __launch_bounds__(256) void norm_trans(const float* __restrict__ x,
                                                  const float* __restrict__ stats,
                                                  const float* __restrict__ gamma,
                                                  const float* __restrict__ beta,
                                                  u16* __restrict__ xnb,
                                                  u16* __restrict__ xnT) {
  __shared__ float tile[32][33];
  int b = blockIdx.z, c0 = blockIdx.y * 32, p0 = blockIdx.x * 32;
  int g = (b << 3) + (c0 >> 6);
  float cnt = 1.f / 262144.f;
  float mu = stats[g * 2 + 0] * cnt;
  float ms = stats[g * 2 + 1] * cnt;
  float rstd = rsqrtf(ms - mu * mu + 1e-5f);
  int tp = threadIdx.x & 31, tc = threadIdx.x >> 5;
#pragma unroll
  for (int r = 0; r < 4; r++) {
    int cl = tc + r * 8;
    int c = c0 + cl;
    long idx = ((long)(b * CDIM + c)) * NPOS + p0 + tp;
    float v = (x[idx] - mu) * rstd * gamma[c] + beta[c];
    xnb[idx] = f2bf(v);
    tile[cl][tp] = v;
  }
  __syncthreads();
#pragma unroll
  for (int r = 0; r < 4; r++) {
    int pl = tc + r * 8, cl = tp;
    xnT[((long)(b * NPOS + p0 + pl)) * CDIM + c0 + cl] = f2bf(tile[cl][pl]);
  }
}

// ------- fp32 -> bf16 weight convert (wq, wk, wv, wp all [512][512]) -------
__global__ __launch_bounds__(256) void cvt4(const float* __restrict__ a, const float* __restrict__ b,
                                            const float* __restrict__ c, const float* __restrict__ d,
                                            u16* __restrict__ oa, u16* __restrict__ ob,
                                            u16* __restrict__ oc, u16* __restrict__ od) {
  int i = blockIdx.x * 256 + threadIdx.x;
  const float* src; u16* dst;
  switch (blockIdx.y) {
    case 0: src = a; dst = oa; break;
    case 1: src = b; dst = ob; break;
    case 2: src = c; dst = oc; break;
    default: src = d; dst = od; break;
  }
  dst[i] = f2bf(src[i]);
}

// ---------------- gemm_bt: C[m,n] = sum_k A[m,k]*B[n,k]  (both K-contig, bf16) ----------------
// 128(M) x BN tile, BK=64, BN/64*2 waves (wave tile 64x64), XOR-swizzled LDS, dbuf.
// MFMA operands SWAPPED: mfma(bfr, af, acc) -> C/D lane dim = m, reg dim = n.
// MODE 0: fp8 out, + bias[n] (bias|bias1 split at n=512)    (fused QK -> fp8)
// MODE 5: fp8 out, + bias[m]                                (V fp8)
// MODE 6: f32  out = acc + bias[m] + bf16 resid             (proj + residual)
template <int MODE, int BN>
__global__ __launch_bounds__(BN * 2, 2) void gemm_bt(
    const u16* __restrict__ A, const u16* __restrict__ B,
    void* __restrict__ Cp, const float* __restrict__ bias,
    const float* __restrict__ bias1, const u16* __restrict__ residb,
    int N, int K, int lda, int ldb,
    long sA, long sB, long sC, long sR) {
  __shared__ u16 Asm[2][128 * 64];
  __shared__ u16 Bsm[2][BN * 64];
  constexpr int NT = BN * 2;       // threads
  constexpr int STEP = NT / 8;     // staging rows per round
  int bz = blockIdx.z;
  A += (long)bz * sA;
  B += (long)bz * sB;
  int bm = blockIdx.y, bn = blockIdx.x;
  int tid = threadIdx.x;
  int lane = tid & 63, wave = tid >> 6;
  int wm = (wave & 1) * 64, wn = (wave >> 1) * 64;

  int row0 = tid >> 3;             // 0..STEP-1
  int ko = (tid & 7) * 8;
  int kos = ko ^ ((row0 & 7) * 8); // STEP multiple of 8 -> row&7 invariant
  f32x4 acc[4][4] = {};
  int row16 = lane & 15;
  int kq = (lane >> 4) * 8;

  auto stage = [&](int buf, int k0) {
#pragma unroll
    for (int r = 0; r < 128 / STEP; r++) {
      int row = row0 + r * STEP;
      async16(A + (long)(bm * 128 + row) * lda + k0 + kos, &Asm[buf][row * 64 + ko]);
    }
#pragma unroll
    for (int r = 0; r < BN / STEP; r++) {
      int row = row0 + r * STEP;
      async16(B + (long)(bn * BN + row) * ldb + k0 + kos, &Bsm[buf][row * 64 + ko]);
    }
  };

  stage(0, 0);
  drain_barrier();
  int cur = 0;
  for (int k0 = 0; k0 < K; k0 += 64) {
    if (k0 + 64 < K) stage(cur ^ 1, k0 + 64);   // prefetch next tile
#pragma unroll
    for (int s2 = 0; s2 < 2; s2++) {
      bf16x8 af[4], bfr[4];
#pragma unroll
      for (int i = 0; i < 4; i++) {
        int row = wm + i * 16 + row16;
        af[i] = *(const bf16x8*)&Asm[cur][row * 64 + ((s2 * 32 + kq) ^ ((row & 7) * 8))];
      }
#pragma unroll
      for (int j = 0; j < 4; j++) {
        int row = wn + j * 16 + row16;
        bfr[j] = *(const bf16x8*)&Bsm[cur][row * 64 + ((s2 * 32 + kq) ^ ((row & 7) * 8))];
      }
      __builtin_amdgcn_s_setprio(1);
#pragma unroll
      for (int i = 0; i < 4; i++)
#pragma unroll
        for (int j = 0; j < 4; j++)
          acc[i][j] = __builtin_amdgcn_mfma_f32_16x16x32_bf16(bfr[j], af[i], acc[i][j], 0, 0, 0);
      __builtin_amdgcn_s_setprio(0);
    }
    drain_barrier();
    cur ^= 1;
  }

  // epilogue (swapped layout): m = lane&15 within tile, n = (lane>>4)*4 + reg
  int mcol = lane & 15, rb = (lane >> 4) * 4;
  long zC = (long)bz * sC;
#pragma unroll
  for (int i = 0; i < 4; i++) {
    int gm = bm * 128 + wm + i * 16 + mcol;
    float bm_add = 0.f;
    if constexpr (MODE == 5 || MODE == 6) bm_add = bias[gm];
#pragma unroll
    for (int j = 0; j < 4; j++) {
      int gn0 = bn * BN + wn + j * 16 + rb;
      long off = zC + (long)gm * N + gn0;
      float v[4];
#pragma unroll
      for (int r = 0; r < 4; r++) v[r] = acc[i][j][r];
      if constexpr (MODE == 0) {
        const float* bb = (gn0 < 512) ? (bias + gn0) : (bias1 + (gn0 - 512));
#pragma unroll
        for (int r = 0; r < 4; r++) v[r] += bb[r];
        *(unsigned*)&((u8*)Cp)[off] = pk4_fp8(v[0], v[1], v[2], v[3]);
      }
      if constexpr (MODE == 5) {
#pragma unroll
        for (int r = 0; r < 4; r++) v[r] += bm_add;
        *(unsigned*)&((u8*)Cp)[off] = pk4_fp8(v[0], v[1], v[2], v[3]);
      }
      if constexpr (MODE == 6) {
        u16x4 rv = *(const u16x4*)&residb[(long)bz * sR + (long)gm * N + gn0];
        f32x4 o;
#pragma unroll
        for (int r = 0; r < 4; r++) o[r] = v[r] + bm_add + bf2f(rv[r]);
        *(f32x4*)&((float*)Cp)[off] = o;
      }
    }
  }
}

// ---------------- fattn: fused S=exp(QK^T*scale) and H=(S.V)/rowsum ----------------
// Grid (64 i-tiles, 1, 4 batches) x 256 thr (4 waves: wi=w>>1, wj=w&1).
// i-tile 64, j-step 64, 64 steps. MX-fp8 MFMA 32x32x64, swapped operands
// (D lane=m(l31), reg n=(r&3)+8*(r>>2)+4*h; A/B frag: lane=row, k-bytes h*32..+31).
// LDS 70KB -> 2 blocks/CU: Ksm [64 j][512B] (32 chunks/row, low3^(j&7));
// Vsm/Pp packed 2 rows per 128B line (R2 scheme): line lr=row>>1, chunk
// g=(row&1)*4 + bytepos>>4, XOR (lr&7). Wave w phase2 c-slice = w*128..+128.
__global__ __launch_bounds__(256, 2) void fattn(const u8* __restrict__ QKf8,
                                                const u8* __restrict__ Vf8,
                                                u16* __restrict__ H, float scale2) {
  __shared__ u8 Ksm[32768];      // [64 j][512 B]
  __shared__ u8 Vsm[32768];      // 256 lines x 128 B (512 c-rows x 64 B)
  __shared__ u8 Pp[4096];        // 32 lines x 128 B (64 i-rows x 64 B)
  __shared__ float lsum[2][64];
  int tid = threadIdx.x, lane = tid & 63, w = tid >> 6;
  int l31 = lane & 31, h = lane >> 5;
  int wi = w >> 1, wj = w & 1;
  int bm = blockIdx.x, bz = blockIdx.z;
  const u8* QKb = QKf8 + (long)bz * 4194304;
  const u8* Vb  = Vf8 + (long)bz * 2097152;

  // Q rows (bm*64 + wi*32 + l31), full c=512, resident in regs (64 VGPR)
  i32x8 qf[8];
  {
    const u8* qrow = QKb + (long)(bm * 64 + wi * 32 + l31) * 1024 + h * 32;
#pragma unroll
    for (int s = 0; s < 8; s++) {
      i32x4 lo = *(const i32x4*)(qrow + s * 64);
      i32x4 hi = *(const i32x4*)(qrow + s * 64 + 16);
      qf[s] = __builtin_shufflevector(lo, hi, 0, 1, 2, 3, 4, 5, 6, 7);
    }
  }

  auto stageK = [&](int t) {
#pragma unroll
    for (int r = 0; r < 8; r++) {
      int zz = tid + r * 256;
      int j = zz >> 5, pos = zz & 31;
      int gch = (pos & 24) | ((pos & 7) ^ (j & 7));
      async16b(QKb + (long)(t * 64 + j) * 1024 + 512 + gch * 16, &Ksm[zz * 16]);
    }
  };
  auto stageV = [&](int t) {
#pragma unroll
    for (int r = 0; r < 8; r++) {
      int zz = tid + r * 256;
      int ldsrow = zz >> 3;
      int gch = (zz & 7) ^ (ldsrow & 7);
      int c = ldsrow * 2 + (gch >> 2);
      int c16 = gch & 3;
      async16b(Vb + (long)c * 4096 + t * 64 + c16 * 16, &Vsm[zz * 16]);
    }
  };

  f32x16 acc[2][4] = {};   // [i-sub][c-sub]; wave c-base = w*128
  float rsum = 0.f;
  int i = wi * 32 + l31;   // this wave's S row (lane)
  int jr = wj * 32 + l31;  // this wave's K row (lane)
  int ilr = i >> 1, isw = ilr & 7;          // P write line / swizzle
  int pgw = (i & 1) * 4;                    // P write chunk base (pre-XOR)

  stageK(0);

  for (int t = 0; t < 64; t++) {
    __syncthreads();              // A: K_t staged+drained; Vsm/Pp reads of t-1 done
    stageV(t);
    // ---- phase 1: S = Q.K^T over c=512 (8 MFMA, regs + Ksm) ----
    f32x16 s16 = {};
#pragma unroll
    for (int s = 0; s < 8; s++) {
      int p0 = 4 * s + 2 * h;
      int pos0 = (p0 & 24) | ((p0 & 7) ^ (jr & 7));
      int pos1 = (p0 & 24) | (((p0 + 1) & 7) ^ (jr & 7));
      i32x4 lo = *(const i32x4*)&Ksm[jr * 512 + pos0 * 16];
      i32x4 hi = *(const i32x4*)&Ksm[jr * 512 + pos1 * 16];
      i32x8 bfk = __builtin_shufflevector(lo, hi, 0, 1, 2, 3, 4, 5, 6, 7);
      __builtin_amdgcn_s_setprio(1);
      s16 = __builtin_amdgcn_mfma_scale_f32_32x32x64_f8f6f4(
          bfk, qf[s], s16, 0, 0, 0, 0x7F7F7F7F, 0, 0x7F7F7F7F);
      __builtin_amdgcn_s_setprio(0);
    }
    // exp2 + rowsum + pack P -> LDS (reg r: j = wj*32 + (r&3) + 8*(r>>2) + 4*h)
    float pv[16];
    float rs = 0.f;
#pragma unroll
    for (int r = 0; r < 16; r++) { pv[r] = exp2f(s16[r] * scale2); rs += pv[r]; }
    rsum += rs + __shfl_xor(rs, 32, 64);
#pragma unroll
    for (int g = 0; g < 4; g++) {
      int jc = wj * 2 + (g >> 1);               // byte-chunk within row (jb>>4)
      int chunk = (pgw + jc) ^ isw;
      *(unsigned*)&Pp[ilr * 128 + chunk * 16 + (g & 1) * 8 + 4 * h] =
          pk4_fp8(pv[4 * g], pv[4 * g + 1], pv[4 * g + 2], pv[4 * g + 3]);
    }
    __syncthreads();              // B: V_t staged+drained; Pp writes visible
    if (t < 63) stageK(t + 1);
    // ---- phase 2: acc += P.V^T over j=64 (k=64, 8 MFMA) ----
    i32x8 afp[2];
#pragma unroll
    for (int mr = 0; mr < 2; mr++) {
      int ii = mr * 32 + l31;
      int lr = ii >> 1, sw = lr & 7;
      int g0 = (ii & 1) * 4 + h * 2;
      i32x4 lo = *(const i32x4*)&Pp[lr * 128 + ((g0) ^ sw) * 16];
      i32x4 hi = *(const i32x4*)&Pp[lr * 128 + ((g0 + 1) ^ sw) * 16];
      afp[mr] = __builtin_shufflevector(lo, hi, 0, 1, 2, 3, 4, 5, 6, 7);
    }
#pragma unroll
    for (int nr = 0; nr < 4; nr++) {
      int c = w * 128 + nr * 32 + l31;
      int lr = c >> 1, sw = lr & 7;
      int g0 = (c & 1) * 4 + h * 2;
      i32x4 lo = *(const i32x4*)&Vsm[lr * 128 + ((g0) ^ sw) * 16];
      i32x4 hi = *(const i32x4*)&Vsm[lr * 128 + ((g0 + 1) ^ sw) * 16];
      i32x8 bfv = __builtin_shufflevector(lo, hi, 0, 1, 2, 3, 4, 5, 6, 7);
      __builtin_amdgcn_s_setprio(1);
#pragma unroll
      for (int mr = 0; mr < 2; mr++)
        acc[mr][nr] = __builtin_amdgcn_mfma_scale_f32_32x32x64_f8f6f4(
            bfv, afp[mr], acc[mr][nr], 0, 0, 0, 0x7F7F7F7F, 0, 0x7F7F7F7F);
      __builtin_amdgcn_s_setprio(0);
    }
  }

  // ---- epilogue: reduce rowsums across wj, divide, store H bf16 ----
  if (lane < 32) lsum[wj][wi * 32 + l31] = rsum;
  __syncthreads();
#pragma unroll
  for (int mr = 0; mr < 2; mr++) {
    int li = mr * 32 + l31;
    float lt = lsum[0][li] + lsum[1][li];
    float inv = 1.f / lt;
    long hrow = ((long)bz * NPOS + bm * 64 + li) * 512;
#pragma unroll
    for (int nr = 0; nr < 4; nr++) {
#pragma unroll
      for (int g = 0; g < 4; g++) {
        u16x4 o;
#pragma unroll
        for (int r = 0; r < 4; r++) o[r] = f2bf(acc[mr][nr][4 * g + r] * inv);
        *(u16x4*)&H[hrow + w * 128 + nr * 32 + 8 * g + 4 * h] = o;
      }
    }
  }
}

extern "C" void kernel_launch(void* const* d_in, const int* in_sizes, int n_in,
                              void* d_out, int out_size, void* d_ws, size_t ws_size,
                              hipStream_t stream) {
  const float* x     = (const float*)d_in[0];
  const float* gamma = (const float*)d_in[1];
  const float* beta  = (const float*)d_in[2];
  const float* wq = (const float*)d_in[3];
  const float* bq = (const float*)d_in[4];
  const float* wk = (const float*)d_in[5];
  const float* bk = (const float*)d_in[6];
  const float* wv = (const float*)d_in[7];
  const float* bv = (const float*)d_in[8];
  const float* wp = (const float*)d_in[9];
  const float* bp = (const float*)d_in[10];
  float* out = (float*)d_out;

  // workspace layout (bytes)
  char* W = (char*)d_ws;
  float* stats = (float*)(W + 0);               // 256 B
  u16* xnb  = (u16*)(W + 65792);                // 16,777,216 bf16 [b,c,p] residual
  u16* xnT  = (u16*)(W + 16843008);             // 16,777,216 bf16 [b,p,c]
  u16* wqkb = (u16*)(W + 33620224);             // 1,048,576  bf16 [1024(cq;ck)][512]
  u16* wvb  = (u16*)(W + 34668800);             // 524,288    bf16 [512][512]
  u16* wpb  = (u16*)(W + 35193088);             // 524,288    bf16 [512][512]
  u8*  QKf8 = (u8*)(W + 37290240);              // 16,777,216 fp8 [b,p,1024] (Q|K)
  u8*  Vf8  = (u8*)(W + 54067456);              // 8,388,608  fp8 [b,c,p]
  u16* Hws  = (u16*)(W + 62456064);             // 16,777,216 bf16 [b,i,512]
  (void)in_sizes; (void)n_in; (void)out_size; (void)ws_size;

  hipMemsetAsync(W, 0, 256, stream);   // stats
  gn_partial<<<256, 256, 0, stream>>>(x, stats);
  norm_trans<<<dim3(128, 16, 4), 256, 0, stream>>>(x, stats, gamma, beta, xnb, xnT);
  cvt4<<<dim3(1024, 4), 256, 0, stream>>>(wq, wk, wv, wp, wqkb, wqkb + 262144, wvb, wpb);

  const long NC = (long)NPOS * CDIM;    // 2,097,152
  const long CN = (long)CDIM * NPOS;
  const float scale = 0.044194173824159216f;        // 1/sqrt(512)
  const float scale2 = scale * 1.4426950408889634f; // 1/sqrt(512) * log2(e)

  // QKf8[b*p, 0:512]=Q, [512:1024]=K (fp8): A=xnT (M=16384), B=wqkb (N=1024), K=512
  gemm_bt<0, 128><<<dim3(8, 128, 1), 256, 0, stream>>>(xnT, wqkb, QKf8, bq, bk, nullptr,
      1024, CDIM, CDIM, CDIM, 0, 0, 0, 0);
  // V fp8 [b][c, p] = wv . xnT_b^T + bv  (M=512, N=4096, K=512)
  gemm_bt<5, 128><<<dim3(32, 4, 4), 256, 0, stream>>>(wvb, xnT, Vf8, bv, nullptr, nullptr,
      NPOS, CDIM, CDIM, CDIM, 0, NC, CN, 0);
  // fused attention: H[b,i,512] = softmax(Q.K^T/sqrt(c)) . V
  fattn<<<dim3(64, 1, NBATCH), 256, 0, stream>>>(QKf8, Vf8, Hws, scale2);
  // out[b][c, p] = wp . H_b^T + bp + xnb  (M=512, N=4096, K=512)
  gemm_bt<6, 128><<<dim3(32, 4, 4), 256, 0, stream>>>(wpb, Hws, (void*)out, bp, nullptr, xnb,
      NPOS, CDIM, CDIM, CDIM, 0, (long)NPOS * CDIM, CN, CN);
}

// Round 5
// 365.720 us; speedup vs baseline: 1.0451x; 1.0451x over previous
//
#include <hip/hip_runtime.h>
#include <hip/hip_bf16.h>

// AttnBlock: x[4,512,64,64] fp32. GroupNorm(8) -> qkv 1x1conv -> attn -> proj -> +xn
// Q,K,V,P fp8 e4m3. R10: fattn = R3 geometry (512 thr / 8 waves, i-tile 64,
// j-step 128, 32 steps, 1 block/CU) with CHUNK-MAJOR LDS layouts:
// Ksm[32 kchunk][128 j][16B], Vsm[8 jchunk][512 c][16B], Pp[8 jchunk][64 i][16B].
// Fragment reads are lane-contiguous (base + lane*16) -> zero bank conflicts,
// no XOR swizzle, immediate-offset ds_reads. Staging permutation moved to the
// per-lane GLOBAL address (LDS dests stay linear). exp2f with folded log2(e).

typedef unsigned short u16;
typedef unsigned char u8;
typedef __bf16 bf16x8 __attribute__((ext_vector_type(8)));
typedef float f32x4 __attribute__((ext_vector_type(4)));
typedef float f32x16 __attribute__((ext_vector_type(16)));
typedef int i32x4 __attribute__((ext_vector_type(4)));
typedef int i32x8 __attribute__((ext_vector_type(8)));
typedef unsigned short u16x4 __attribute__((ext_vector_type(4)));

#define CDIM 512
#define NPOS 4096
#define NBATCH 4

__device__ __forceinline__ u16 f2bf(float x) {
  union { float f; unsigned u; } c; c.f = x;
  unsigned u = c.u;
  u += 0x7fffu + ((u >> 16) & 1u);   // round-to-nearest-even
  return (u16)(u >> 16);
}
__device__ __forceinline__ float bf2f(u16 h) {
  union { unsigned u; float f; } c; c.u = ((unsigned)h) << 16;
  return c.f;
}
// pack 4 floats -> 4 fp8 e4m3 bytes
__device__ __forceinline__ unsigned pk4_fp8(float a, float b, float c, float d) {
  unsigned v = __builtin_amdgcn_cvt_pk_fp8_f32(a, b, 0, false);
  v = __builtin_amdgcn_cvt_pk_fp8_f32(c, d, v, true);
  return v;
}

__device__ __forceinline__ void async16(const u16* g, u16* l) {
  __builtin_amdgcn_global_load_lds(
      (const __attribute__((address_space(1))) unsigned int*)g,
      (__attribute__((address_space(3))) unsigned int*)l, 16, 0, 0);
}
__device__ __forceinline__ void async16b(const u8* g, u8* l) {
  __builtin_amdgcn_global_load_lds(
      (const __attribute__((address_space(1))) unsigned int*)g,
      (__attribute__((address_space(3))) unsigned int*)l, 16, 0, 0);
}

__device__ __forceinline__ void drain_barrier() {
  asm volatile("s_waitcnt vmcnt(0)" ::: "memory");
  __builtin_amdgcn_s_barrier();
}

__device__ __forceinline__ float wred_sum(float v) {
#pragma unroll
  for (int o = 32; o > 0; o >>= 1) v += __shfl_xor(v, o, 64);
  return v;
}

// ---------------- GroupNorm stats: 32 (b,g) groups x 8 slices ----------------
__global__ __launch_bounds__(256) void gn_partial(const float* __restrict__ x,
                                                  float* __restrict__ stats) {
  int gidx = blockIdx.x >> 3;
  int slice = blockIdx.x & 7;
  const float4* src = (const float4*)x + (long)gidx * 65536 + (long)slice * 8192;
  float s = 0.f, ss = 0.f;
  for (int i = threadIdx.x; i < 8192; i += 256) {
    float4 v = src[i];
    s  += v.x + v.y + v.z + v.w;
    ss += v.x * v.x + v.y * v.y + v.z * v.z + v.w * v.w;
  }
  s = wred_sum(s); ss = wred_sum(ss);
  __shared__ float r1[4], r2[4];
  int lane = threadIdx.x & 63, wave = threadIdx.x >> 6;
  if (lane == 0) { r1[wave] = s; r2[wave] = ss; }
  __syncthreads();
  if (threadIdx.x == 0) {
    atomicAdd(&stats[gidx * 2 + 0], r1[0] + r1[1] + r1[2] + r1[3]);
    atomicAdd(&stats[gidx * 2 + 1], r2[0] + r2[1] + r2[2] + r2[3]);
  }
}

// ------- normalize + write xnb bf16 [b,c,p] (residual) and xnT bf16 [b,p,c] -------
__global__ __launch_bounds__(256) void norm_trans(const float* __restrict__ x,
                                                  const float* __restrict__ stats,
                                                  const float* __restrict__ gamma,
                                                  const float* __restrict__ beta,
                                                  u16* __restrict__ xnb,
                                                  u16* __restrict__ xnT) {
  __shared__ float tile[32][33];
  int b = blockIdx.z, c0 = blockIdx.y * 32, p0 = blockIdx.x * 32;
  int g = (b << 3) + (c0 >> 6);
  float cnt = 1.f / 262144.f;
  float mu = stats[g * 2 + 0] * cnt;
  float ms = stats[g * 2 + 1] * cnt;
  float rstd = rsqrtf(ms - mu * mu + 1e-5f);
  int tp = threadIdx.x & 31, tc = threadIdx.x >> 5;
#pragma unroll
  for (int r = 0; r < 4; r++) {
    int cl = tc + r * 8;
    int c = c0 + cl;
    long idx = ((long)(b * CDIM + c)) * NPOS + p0 + tp;
    float v = (x[idx] - mu) * rstd * gamma[c] + beta[c];
    xnb[idx] = f2bf(v);
    tile[cl][tp] = v;
  }
  __syncthreads();
#pragma unroll
  for (int r = 0; r < 4; r++) {
    int pl = tc + r * 8, cl = tp;
    xnT[((long)(b * NPOS + p0 + pl)) * CDIM + c0 + cl] = f2bf(tile[cl][pl]);
  }
}

// ------- fp32 -> bf16 weight convert (wq, wk, wv, wp all [512][512]) -------
__global__ __launch_bounds__(256) void cvt4(const float* __restrict__ a, const float* __restrict__ b,
                                            const float* __restrict__ c, const float* __restrict__ d,
                                            u16* __restrict__ oa, u16* __restrict__ ob,
                                            u16* __restrict__ oc, u16* __restrict__ od) {
  int i = blockIdx.x * 256 + threadIdx.x;
  const float* src; u16* dst;
  switch (blockIdx.y) {
    case 0: src = a; dst = oa; break;
    case 1: src = b; dst = ob; break;
    case 2: src = c; dst = oc; break;
    default: src = d; dst = od; break;
  }
  dst[i] = f2bf(src[i]);
}

// ---------------- gemm_bt: C[m,n] = sum_k A[m,k]*B[n,k]  (both K-contig, bf16) ----------------
// 128(M) x BN tile, BK=64, BN/64*2 waves (wave tile 64x64), XOR-swizzled LDS, dbuf.
// MFMA operands SWAPPED: mfma(bfr, af, acc) -> C/D lane dim = m, reg dim = n.
// MODE 0: fp8 out, + bias[n] (bias|bias1 split at n=512)    (fused QK -> fp8)
// MODE 5: fp8 out, + bias[m]                                (V fp8)
// MODE 6: f32  out = acc + bias[m] + bf16 resid             (proj + residual)
template <int MODE, int BN>
__global__ __launch_bounds__(BN * 2, 2) void gemm_bt(
    const u16* __restrict__ A, const u16* __restrict__ B,
    void* __restrict__ Cp, const float* __restrict__ bias,
    const float* __restrict__ bias1, const u16* __restrict__ residb,
    int N, int K, int lda, int ldb,
    long sA, long sB, long sC, long sR) {
  __shared__ u16 Asm[2][128 * 64];
  __shared__ u16 Bsm[2][BN * 64];
  constexpr int NT = BN * 2;       // threads
  constexpr int STEP = NT / 8;     // staging rows per round
  int bz = blockIdx.z;
  A += (long)bz * sA;
  B += (long)bz * sB;
  int bm = blockIdx.y, bn = blockIdx.x;
  int tid = threadIdx.x;
  int lane = tid & 63, wave = tid >> 6;
  int wm = (wave & 1) * 64, wn = (wave >> 1) * 64;

  int row0 = tid >> 3;             // 0..STEP-1
  int ko = (tid & 7) * 8;
  int kos = ko ^ ((row0 & 7) * 8); // STEP multiple of 8 -> row&7 invariant
  f32x4 acc[4][4] = {};
  int row16 = lane & 15;
  int kq = (lane >> 4) * 8;

  auto stage = [&](int buf, int k0) {
#pragma unroll
    for (int r = 0; r < 128 / STEP; r++) {
      int row = row0 + r * STEP;
      async16(A + (long)(bm * 128 + row) * lda + k0 + kos, &Asm[buf][row * 64 + ko]);
    }
#pragma unroll
    for (int r = 0; r < BN / STEP; r++) {
      int row = row0 + r * STEP;
      async16(B + (long)(bn * BN + row) * ldb + k0 + kos, &Bsm[buf][row * 64 + ko]);
    }
  };

  stage(0, 0);
  drain_barrier();
  int cur = 0;
  for (int k0 = 0; k0 < K; k0 += 64) {
    if (k0 + 64 < K) stage(cur ^ 1, k0 + 64);   // prefetch next tile
#pragma unroll
    for (int s2 = 0; s2 < 2; s2++) {
      bf16x8 af[4], bfr[4];
#pragma unroll
      for (int i = 0; i < 4; i++) {
        int row = wm + i * 16 + row16;
        af[i] = *(const bf16x8*)&Asm[cur][row * 64 + ((s2 * 32 + kq) ^ ((row & 7) * 8))];
      }
#pragma unroll
      for (int j = 0; j < 4; j++) {
        int row = wn + j * 16 + row16;
        bfr[j] = *(const bf16x8*)&Bsm[cur][row * 64 + ((s2 * 32 + kq) ^ ((row & 7) * 8))];
      }
      __builtin_amdgcn_s_setprio(1);
#pragma unroll
      for (int i = 0; i < 4; i++)
#pragma unroll
        for (int j = 0; j < 4; j++)
          acc[i][j] = __builtin_amdgcn_mfma_f32_16x16x32_bf16(bfr[j], af[i], acc[i][j], 0, 0, 0);
      __builtin_amdgcn_s_setprio(0);
    }
    drain_barrier();
    cur ^= 1;
  }

  // epilogue (swapped layout): m = lane&15 within tile, n = (lane>>4)*4 + reg
  int mcol = lane & 15, rb = (lane >> 4) * 4;
  long zC = (long)bz * sC;
#pragma unroll
  for (int i = 0; i < 4; i++) {
    int gm = bm * 128 + wm + i * 16 + mcol;
    float bm_add = 0.f;
    if constexpr (MODE == 5 || MODE == 6) bm_add = bias[gm];
#pragma unroll
    for (int j = 0; j < 4; j++) {
      int gn0 = bn * BN + wn + j * 16 + rb;
      long off = zC + (long)gm * N + gn0;
      float v[4];
#pragma unroll
      for (int r = 0; r < 4; r++) v[r] = acc[i][j][r];
      if constexpr (MODE == 0) {
        const float* bb = (gn0 < 512) ? (bias + gn0) : (bias1 + (gn0 - 512));
#pragma unroll
        for (int r = 0; r < 4; r++) v[r] += bb[r];
        *(unsigned*)&((u8*)Cp)[off] = pk4_fp8(v[0], v[1], v[2], v[3]);
      }
      if constexpr (MODE == 5) {
#pragma unroll
        for (int r = 0; r < 4; r++) v[r] += bm_add;
        *(unsigned*)&((u8*)Cp)[off] = pk4_fp8(v[0], v[1], v[2], v[3]);
      }
      if constexpr (MODE == 6) {
        u16x4 rv = *(const u16x4*)&residb[(long)bz * sR + (long)gm * N + gn0];
        f32x4 o;
#pragma unroll
        for (int r = 0; r < 4; r++) o[r] = v[r] + bm_add + bf2f(rv[r]);
        *(f32x4*)&((float*)Cp)[off] = o;
      }
    }
  }
}

// ---------------- fattn: fused S=exp(QK^T*scale) and H=(S.V)/rowsum ----------------
// Grid (64 i-tiles, 1, 4 batches) x 512 thr (8 waves: wi=w>>2 (2), wj=w&3 (4)).
// i-tile 64, j-step 128, 32 steps. MX-fp8 MFMA 32x32x64, swapped operands
// (D lane=m(l31), reg n=(r&3)+8*(r>>2)+4*h; A/B frag: lane=row, k-bytes h*32..+31).
// CHUNK-MAJOR LDS (conflict-free reads, no swizzle):
//   Ksm[kchunk 32][j 128][16B]: frag read addr = (4s+2h)*2048 + jr*16 (+2048)
//   Vsm[jchunk 8][c 512][16B]:  frag read addr = (4kk+2h)*8192 + c*16 (+8192)
//   Pp [jchunk 8][i 64][16B]:   frag read addr = (4kk+2h)*1024 + ii*16 (+1024)
// Per step: syncA (K_t drained); stage V_t; S=QK (8 MFMA, c=512); exp2 -> P LDS
// + rowsum; syncB (V_t drained, P visible); stage K_{t+1}; acc += P.V^T (8 MFMA).
__global__ __launch_bounds__(512, 2) void fattn(const u8* __restrict__ QKf8,
                                                const u8* __restrict__ Vf8,
                                                u16* __restrict__ H, float scale2) {
  __shared__ u8 Ksm[65536];      // 32 kchunks x 128 j x 16B
  __shared__ u8 Vsm[65536];      // 8 jchunks x 512 c x 16B
  __shared__ u8 Pp[8192];        // 8 jchunks x 64 i x 16B
  __shared__ float lsum[4][64];
  int tid = threadIdx.x, lane = tid & 63, w = tid >> 6;
  int l31 = lane & 31, h = lane >> 5;
  int wi = w >> 2, wj = w & 3;
  int bm = blockIdx.x, bz = blockIdx.z;
  const u8* QKb = QKf8 + (long)bz * 4194304;
  const u8* Vb  = Vf8 + (long)bz * 2097152;

  // Q rows (bm*64 + wi*32 + l31), full c=512, resident in regs (64 VGPR)
  i32x8 qf[8];
  {
    const u8* qrow = QKb + (long)(bm * 64 + wi * 32 + l31) * 1024 + h * 32;
#pragma unroll
    for (int s = 0; s < 8; s++) {
      i32x4 lo = *(const i32x4*)(qrow + s * 64);
      i32x4 hi = *(const i32x4*)(qrow + s * 64 + 16);
      qf[s] = __builtin_shufflevector(lo, hi, 0, 1, 2, 3, 4, 5, 6, 7);
    }
  }

  // stage K_t: slot zz -> kchunk = zz>>7, j = zz&127 (LDS linear, perm in src)
  auto stageK = [&](int t) {
#pragma unroll
    for (int r = 0; r < 8; r++) {
      int zz = tid + r * 512;
      int ch = zz >> 7, j = zz & 127;
      async16b(QKb + (long)(t * 128 + j) * 1024 + 512 + ch * 16, &Ksm[zz * 16]);
    }
  };
  // stage V_t: slot zz -> jchunk = zz>>9, c = zz&511
  auto stageV = [&](int t) {
#pragma unroll
    for (int r = 0; r < 8; r++) {
      int zz = tid + r * 512;
      int jc = zz >> 9, c = zz & 511;
      async16b(Vb + (long)c * 4096 + t * 128 + jc * 16, &Vsm[zz * 16]);
    }
  };

  f32x16 acc[2][2] = {};   // [i-sub][c-sub]; wave c-base = w*64
  float rsum = 0.f;
  int i = wi * 32 + l31;   // this wave's S row (lane)
  int jr = wj * 32 + l31;  // this wave's K row (lane)

  stageK(0);

  for (int t = 0; t < 32; t++) {
    __syncthreads();              // A: K_t staged+drained; Vsm/Pp reads of t-1 done
    stageV(t);
    // ---- phase 1: S = Q.K^T over c=512 (8 MFMA, regs + Ksm) ----
    f32x16 s16 = {};
#pragma unroll
    for (int s = 0; s < 8; s++) {
      int a0 = (4 * s + 2 * h) * 2048 + jr * 16;
      i32x4 lo = *(const i32x4*)&Ksm[a0];
      i32x4 hi = *(const i32x4*)&Ksm[a0 + 2048];
      i32x8 bfk = __builtin_shufflevector(lo, hi, 0, 1, 2, 3, 4, 5, 6, 7);
      __builtin_amdgcn_s_setprio(1);
      s16 = __builtin_amdgcn_mfma_scale_f32_32x32x64_f8f6f4(
          bfk, qf[s], s16, 0, 0, 0, 0x7F7F7F7F, 0, 0x7F7F7F7F);
      __builtin_amdgcn_s_setprio(0);
    }
    // exp2 + rowsum + pack P -> LDS (reg r: j = wj*32 + (r&3) + 8*(r>>2) + 4*h)
    float pv[16];
    float rs = 0.f;
#pragma unroll
    for (int r = 0; r < 16; r++) { pv[r] = exp2f(s16[r] * scale2); rs += pv[r]; }
    rsum += rs + __shfl_xor(rs, 32, 64);
#pragma unroll
    for (int g = 0; g < 4; g++) {
      int jc = wj * 2 + (g >> 1);
      *(unsigned*)&Pp[jc * 1024 + i * 16 + 8 * (g & 1) + 4 * h] =
          pk4_fp8(pv[4 * g], pv[4 * g + 1], pv[4 * g + 2], pv[4 * g + 3]);
    }
    __syncthreads();              // B: V_t staged+drained; Pp writes visible
    if (t < 31) stageK(t + 1);
    // ---- phase 2: acc += P.V^T over local j=128 (2 MFMA k-steps) ----
#pragma unroll
    for (int kk = 0; kk < 2; kk++) {
      int kb = (4 * kk + 2 * h);
      i32x8 afp[2], bfv[2];
#pragma unroll
      for (int mr = 0; mr < 2; mr++) {
        int ii = mr * 32 + l31;
        i32x4 lo = *(const i32x4*)&Pp[kb * 1024 + ii * 16];
        i32x4 hi = *(const i32x4*)&Pp[(kb + 1) * 1024 + ii * 16];
        afp[mr] = __builtin_shufflevector(lo, hi, 0, 1, 2, 3, 4, 5, 6, 7);
      }
#pragma unroll
      for (int nr = 0; nr < 2; nr++) {
        int c = w * 64 + nr * 32 + l31;
        i32x4 lo = *(const i32x4*)&Vsm[kb * 8192 + c * 16];
        i32x4 hi = *(const i32x4*)&Vsm[(kb + 1) * 8192 + c * 16];
        bfv[nr] = __builtin_shufflevector(lo, hi, 0, 1, 2, 3, 4, 5, 6, 7);
      }
      __builtin_amdgcn_s_setprio(1);
#pragma unroll
      for (int mr = 0; mr < 2; mr++)
#pragma unroll
        for (int nr = 0; nr < 2; nr++)
          acc[mr][nr] = __builtin_amdgcn_mfma_scale_f32_32x32x64_f8f6f4(
              bfv[nr], afp[mr], acc[mr][nr], 0, 0, 0, 0x7F7F7F7F, 0, 0x7F7F7F7F);
      __builtin_amdgcn_s_setprio(0);
    }
  }

  // ---- epilogue: reduce rowsums across wj, divide, store H bf16 ----
  if (lane < 32) lsum[wj][wi * 32 + l31] = rsum;
  __syncthreads();
#pragma unroll
  for (int mr = 0; mr < 2; mr++) {
    int li = mr * 32 + l31;
    float lt = lsum[0][li] + lsum[1][li] + lsum[2][li] + lsum[3][li];
    float inv = 1.f / lt;
    long hrow = ((long)bz * NPOS + bm * 64 + li) * 512;
#pragma unroll
    for (int nr = 0; nr < 2; nr++) {
#pragma unroll
      for (int g = 0; g < 4; g++) {
        u16x4 o;
#pragma unroll
        for (int r = 0; r < 4; r++) o[r] = f2bf(acc[mr][nr][4 * g + r] * inv);
        *(u16x4*)&H[hrow + w * 64 + nr * 32 + 8 * g + 4 * h] = o;
      }
    }
  }
}

extern "C" void kernel_launch(void* const* d_in, const int* in_sizes, int n_in,
                              void* d_out, int out_size, void* d_ws, size_t ws_size,
                              hipStream_t stream) {
  const float* x     = (const float*)d_in[0];
  const float* gamma = (const float*)d_in[1];
  const float* beta  = (const float*)d_in[2];
  const float* wq = (const float*)d_in[3];
  const float* bq = (const float*)d_in[4];
  const float* wk = (const float*)d_in[5];
  const float* bk = (const float*)d_in[6];
  const float* wv = (const float*)d_in[7];
  const float* bv = (const float*)d_in[8];
  const float* wp = (const float*)d_in[9];
  const float* bp = (const float*)d_in[10];
  float* out = (float*)d_out;

  // workspace layout (bytes)
  char* W = (char*)d_ws;
  float* stats = (float*)(W + 0);               // 256 B
  u16* xnb  = (u16*)(W + 65792);                // 16,777,216 bf16 [b,c,p] residual
  u16* xnT  = (u16*)(W + 16843008);             // 16,777,216 bf16 [b,p,c]
  u16* wqkb = (u16*)(W + 33620224);             // 1,048,576  bf16 [1024(cq;ck)][512]
  u16* wvb  = (u16*)(W + 34668800);             // 524,288    bf16 [512][512]
  u16* wpb  = (u16*)(W + 35193088);             // 524,288    bf16 [512][512]
  u8*  QKf8 = (u8*)(W + 37290240);              // 16,777,216 fp8 [b,p,1024] (Q|K)
  u8*  Vf8  = (u8*)(W + 54067456);              // 8,388,608  fp8 [b,c,p]
  u16* Hws  = (u16*)(W + 62456064);             // 16,777,216 bf16 [b,i,512]
  (void)in_sizes; (void)n_in; (void)out_size; (void)ws_size;

  hipMemsetAsync(W, 0, 256, stream);   // stats
  gn_partial<<<256, 256, 0, stream>>>(x, stats);
  norm_trans<<<dim3(128, 16, 4), 256, 0, stream>>>(x, stats, gamma, beta, xnb, xnT);
  cvt4<<<dim3(1024, 4), 256, 0, stream>>>(wq, wk, wv, wp, wqkb, wqkb + 262144, wvb, wpb);

  const long NC = (long)NPOS * CDIM;    // 2,097,152
  const long CN = (long)CDIM * NPOS;
  const float scale = 0.044194173824159216f;        // 1/sqrt(512)
  const float scale2 = scale * 1.4426950408889634f; // 1/sqrt(512) * log2(e)

  // QKf8[b*p, 0:512]=Q, [512:1024]=K (fp8): A=xnT (M=16384), B=wqkb (N=1024), K=512
  gemm_bt<0, 128><<<dim3(8, 128, 1), 256, 0, stream>>>(xnT, wqkb, QKf8, bq, bk, nullptr,
      1024, CDIM, CDIM, CDIM, 0, 0, 0, 0);
  // V fp8 [b][c, p] = wv . xnT_b^T + bv  (M=512, N=4096, K=512)
  gemm_bt<5, 128><<<dim3(32, 4, 4), 256, 0, stream>>>(wvb, xnT, Vf8, bv, nullptr, nullptr,
      NPOS, CDIM, CDIM, CDIM, 0, NC, CN, 0);
  // fused attention: H[b,i,512] = softmax(Q.K^T/sqrt(c)) . V
  fattn<<<dim3(64, 1, NBATCH), 512, 0, stream>>>(QKf8, Vf8, Hws, scale2);
  // out[b][c, p] = wp . H_b^T + bp + xnb  (M=512, N=4096, K=512)
  gemm_bt<6, 128><<<dim3(32, 4, 4), 256, 0, stream>>>(wpb, Hws, (void*)out, bp, nullptr, xnb,
      NPOS, CDIM, CDIM, CDIM, 0, (long)NPOS * CDIM, CN, CN);
}

// Round 6
// 326.268 us; speedup vs baseline: 1.1715x; 1.1209x over previous
//
#include <hip/hip_runtime.h>
#include <hip/hip_bf16.h>

// AttnBlock: x[4,512,64,64] fp32. GroupNorm(8) -> qkv 1x1conv -> attn -> proj -> +xn
// Q,K,V,P fp8 e4m3. R11: fattn = R3 geometry (512thr/8 waves, i-tile 64, j-step 128,
// 32 steps) restructured for LDS-bound regime:
//  - 1 full (vmcnt0) + 2 light (lgkm-only) barriers/step; K single-buffered
//    (light-bar after S-phase reads), V single-buffered via reg-preload of V frags
//    before overwrite, P double-buffered (PV lags S by one step).
//  - P chunk-major [8 jc][64 i][16B] (R5-verified formulas): conflict-free P reads.
//  - K/V keep R3 row-major+XOR gll-coalesced layouts (R5 lesson: global side of
//    global_load_lds must stay coalesced; only within-row chunk permutes legal).
//  - XCD swizzle: lid%8 = XCD under round-robin; 2 XCDs per batch so each XCD's
//    4MB L2 holds exactly one batch's K+V (cuts the 3x L2-miss over-fetch).

typedef unsigned short u16;
typedef unsigned char u8;
typedef __bf16 bf16x8 __attribute__((ext_vector_type(8)));
typedef float f32x4 __attribute__((ext_vector_type(4)));
typedef float f32x16 __attribute__((ext_vector_type(16)));
typedef int i32x4 __attribute__((ext_vector_type(4)));
typedef int i32x8 __attribute__((ext_vector_type(8)));
typedef unsigned short u16x4 __attribute__((ext_vector_type(4)));

#define CDIM 512
#define NPOS 4096
#define NBATCH 4

__device__ __forceinline__ u16 f2bf(float x) {
  union { float f; unsigned u; } c; c.f = x;
  unsigned u = c.u;
  u += 0x7fffu + ((u >> 16) & 1u);   // round-to-nearest-even
  return (u16)(u >> 16);
}
__device__ __forceinline__ float bf2f(u16 h) {
  union { unsigned u; float f; } c; c.u = ((unsigned)h) << 16;
  return c.f;
}
// pack 4 floats -> 4 fp8 e4m3 bytes
__device__ __forceinline__ unsigned pk4_fp8(float a, float b, float c, float d) {
  unsigned v = __builtin_amdgcn_cvt_pk_fp8_f32(a, b, 0, false);
  v = __builtin_amdgcn_cvt_pk_fp8_f32(c, d, v, true);
  return v;
}

__device__ __forceinline__ void async16(const u16* g, u16* l) {
  __builtin_amdgcn_global_load_lds(
      (const __attribute__((address_space(1))) unsigned int*)g,
      (__attribute__((address_space(3))) unsigned int*)l, 16, 0, 0);
}
__device__ __forceinline__ void async16b(const u8* g, u8* l) {
  __builtin_amdgcn_global_load_lds(
      (const __attribute__((address_space(1))) unsigned int*)g,
      (__attribute__((address_space(3))) unsigned int*)l, 16, 0, 0);
}

__device__ __forceinline__ void drain_barrier() {
  asm volatile("s_waitcnt vmcnt(0)" ::: "memory");
  __builtin_amdgcn_s_barrier();
}
__device__ __forceinline__ void vm_barrier() {
  asm volatile("s_waitcnt vmcnt(0)" ::: "memory");
  __builtin_amdgcn_s_barrier();
}
__device__ __forceinline__ void lgkm_barrier() {
  asm volatile("s_waitcnt lgkmcnt(0)" ::: "memory");
  __builtin_amdgcn_s_barrier();
}

__device__ __forceinline__ float wred_sum(float v) {
#pragma unroll
  for (int o = 32; o > 0; o >>= 1) v += __shfl_xor(v, o, 64);
  return v;
}

// ---------------- GroupNorm stats: 32 (b,g) groups x 8 slices ----------------
__global__ __launch_bounds__(256) void gn_partial(const float* __restrict__ x,
                                                  float* __restrict__ stats) {
  int gidx = blockIdx.x >> 3;
  int slice = blockIdx.x & 7;
  const float4* src = (const float4*)x + (long)gidx * 65536 + (long)slice * 8192;
  float s = 0.f, ss = 0.f;
  for (int i = threadIdx.x; i < 8192; i += 256) {
    float4 v = src[i];
    s  += v.x + v.y + v.z + v.w;
    ss += v.x * v.x + v.y * v.y + v.z * v.z + v.w * v.w;
  }
  s = wred_sum(s); ss = wred_sum(ss);
  __shared__ float r1[4], r2[4];
  int lane = threadIdx.x & 63, wave = threadIdx.x >> 6;
  if (lane == 0) { r1[wave] = s; r2[wave] = ss; }
  __syncthreads();
  if (threadIdx.x == 0) {
    atomicAdd(&stats[gidx * 2 + 0], r1[0] + r1[1] + r1[2] + r1[3]);
    atomicAdd(&stats[gidx * 2 + 1], r2[0] + r2[1] + r2[2] + r2[3]);
  }
}

// ------- normalize + write xnb bf16 [b,c,p] (residual) and xnT bf16 [b,p,c] -------
__global__ __launch_bounds__(256) void norm_trans(const float* __restrict__ x,
                                                  const float* __restrict__ stats,
                                                  const float* __restrict__ gamma,
                                                  const float* __restrict__ beta,
                                                  u16* __restrict__ xnb,
                                                  u16* __restrict__ xnT) {
  __shared__ float tile[32][33];
  int b = blockIdx.z, c0 = blockIdx.y * 32, p0 = blockIdx.x * 32;
  int g = (b << 3) + (c0 >> 6);
  float cnt = 1.f / 262144.f;
  float mu = stats[g * 2 + 0] * cnt;
  float ms = stats[g * 2 + 1] * cnt;
  float rstd = rsqrtf(ms - mu * mu + 1e-5f);
  int tp = threadIdx.x & 31, tc = threadIdx.x >> 5;
#pragma unroll
  for (int r = 0; r < 4; r++) {
    int cl = tc + r * 8;
    int c = c0 + cl;
    long idx = ((long)(b * CDIM + c)) * NPOS + p0 + tp;
    float v = (x[idx] - mu) * rstd * gamma[c] + beta[c];
    xnb[idx] = f2bf(v);
    tile[cl][tp] = v;
  }
  __syncthreads();
#pragma unroll
  for (int r = 0; r < 4; r++) {
    int pl = tc + r * 8, cl = tp;
    xnT[((long)(b * NPOS + p0 + pl)) * CDIM + c0 + cl] = f2bf(tile[cl][pl]);
  }
}

// ------- fp32 -> bf16 weight convert (wq, wk, wv, wp all [512][512]) -------
__global__ __launch_bounds__(256) void cvt4(const float* __restrict__ a, const float* __restrict__ b,
                                            const float* __restrict__ c, const float* __restrict__ d,
                                            u16* __restrict__ oa, u16* __restrict__ ob,
                                            u16* __restrict__ oc, u16* __restrict__ od) {
  int i = blockIdx.x * 256 + threadIdx.x;
  const float* src; u16* dst;
  switch (blockIdx.y) {
    case 0: src = a; dst = oa; break;
    case 1: src = b; dst = ob; break;
    case 2: src = c; dst = oc; break;
    default: src = d; dst = od; break;
  }
  dst[i] = f2bf(src[i]);
}

// ---------------- gemm_bt: C[m,n] = sum_k A[m,k]*B[n,k]  (both K-contig, bf16) ----------------
// 128(M) x BN tile, BK=64, BN/64*2 waves (wave tile 64x64), XOR-swizzled LDS, dbuf.
// MFMA operands SWAPPED: mfma(bfr, af, acc) -> C/D lane dim = m, reg dim = n.
// MODE 0: fp8 out, + bias[n] (bias|bias1 split at n=512)    (fused QK -> fp8)
// MODE 5: fp8 out, + bias[m]                                (V fp8)
// MODE 6: f32  out = acc + bias[m] + bf16 resid             (proj + residual)
template <int MODE, int BN>
__global__ __launch_bounds__(BN * 2, 2) void gemm_bt(
    const u16* __restrict__ A, const u16* __restrict__ B,
    void* __restrict__ Cp, const float* __restrict__ bias,
    const float* __restrict__ bias1, const u16* __restrict__ residb,
    int N, int K, int lda, int ldb,
    long sA, long sB, long sC, long sR) {
  __shared__ u16 Asm[2][128 * 64];
  __shared__ u16 Bsm[2][BN * 64];
  constexpr int NT = BN * 2;       // threads
  constexpr int STEP = NT / 8;     // staging rows per round
  int bz = blockIdx.z;
  A += (long)bz * sA;
  B += (long)bz * sB;
  int bm = blockIdx.y, bn = blockIdx.x;
  int tid = threadIdx.x;
  int lane = tid & 63, wave = tid >> 6;
  int wm = (wave & 1) * 64, wn = (wave >> 1) * 64;

  int row0 = tid >> 3;             // 0..STEP-1
  int ko = (tid & 7) * 8;
  int kos = ko ^ ((row0 & 7) * 8); // STEP multiple of 8 -> row&7 invariant
  f32x4 acc[4][4] = {};
  int row16 = lane & 15;
  int kq = (lane >> 4) * 8;

  auto stage = [&](int buf, int k0) {
#pragma unroll
    for (int r = 0; r < 128 / STEP; r++) {
      int row = row0 + r * STEP;
      async16(A + (long)(bm * 128 + row) * lda + k0 + kos, &Asm[buf][row * 64 + ko]);
    }
#pragma unroll
    for (int r = 0; r < BN / STEP; r++) {
      int row = row0 + r * STEP;
      async16(B + (long)(bn * BN + row) * ldb + k0 + kos, &Bsm[buf][row * 64 + ko]);
    }
  };

  stage(0, 0);
  drain_barrier();
  int cur = 0;
  for (int k0 = 0; k0 < K; k0 += 64) {
    if (k0 + 64 < K) stage(cur ^ 1, k0 + 64);   // prefetch next tile
#pragma unroll
    for (int s2 = 0; s2 < 2; s2++) {
      bf16x8 af[4], bfr[4];
#pragma unroll
      for (int i = 0; i < 4; i++) {
        int row = wm + i * 16 + row16;
        af[i] = *(const bf16x8*)&Asm[cur][row * 64 + ((s2 * 32 + kq) ^ ((row & 7) * 8))];
      }
#pragma unroll
      for (int j = 0; j < 4; j++) {
        int row = wn + j * 16 + row16;
        bfr[j] = *(const bf16x8*)&Bsm[cur][row * 64 + ((s2 * 32 + kq) ^ ((row & 7) * 8))];
      }
      __builtin_amdgcn_s_setprio(1);
#pragma unroll
      for (int i = 0; i < 4; i++)
#pragma unroll
        for (int j = 0; j < 4; j++)
          acc[i][j] = __builtin_amdgcn_mfma_f32_16x16x32_bf16(bfr[j], af[i], acc[i][j], 0, 0, 0);
      __builtin_amdgcn_s_setprio(0);
    }
    drain_barrier();
    cur ^= 1;
  }

  // epilogue (swapped layout): m = lane&15 within tile, n = (lane>>4)*4 + reg
  int mcol = lane & 15, rb = (lane >> 4) * 4;
  long zC = (long)bz * sC;
#pragma unroll
  for (int i = 0; i < 4; i++) {
    int gm = bm * 128 + wm + i * 16 + mcol;
    float bm_add = 0.f;
    if constexpr (MODE == 5 || MODE == 6) bm_add = bias[gm];
#pragma unroll
    for (int j = 0; j < 4; j++) {
      int gn0 = bn * BN + wn + j * 16 + rb;
      long off = zC + (long)gm * N + gn0;
      float v[4];
#pragma unroll
      for (int r = 0; r < 4; r++) v[r] = acc[i][j][r];
      if constexpr (MODE == 0) {
        const float* bb = (gn0 < 512) ? (bias + gn0) : (bias1 + (gn0 - 512));
#pragma unroll
        for (int r = 0; r < 4; r++) v[r] += bb[r];
        *(unsigned*)&((u8*)Cp)[off] = pk4_fp8(v[0], v[1], v[2], v[3]);
      }
      if constexpr (MODE == 5) {
#pragma unroll
        for (int r = 0; r < 4; r++) v[r] += bm_add;
        *(unsigned*)&((u8*)Cp)[off] = pk4_fp8(v[0], v[1], v[2], v[3]);
      }
      if constexpr (MODE == 6) {
        u16x4 rv = *(const u16x4*)&residb[(long)bz * sR + (long)gm * N + gn0];
        f32x4 o;
#pragma unroll
        for (int r = 0; r < 4; r++) o[r] = v[r] + bm_add + bf2f(rv[r]);
        *(f32x4*)&((float*)Cp)[off] = o;
      }
    }
  }
}

// ---------------- fattn: fused S=exp(QK^T*scale) and H=(S.V)/rowsum ----------------
// 256 blocks (XCD-swizzled), 512 thr (8 waves: wi=w>>2, wj=w&3). i-tile 64,
// j-step 128, 32 steps; PV lags S by one step (P dbuf).
// Per iter t: [vm_barrier: K(t),V(t-1) staged] phaseA: S(t)=Q.K(t) (Ksm R3 layout),
// exp2 -> P(t)->Pp[t&1] (chunk-major), rowsum; [lgkm_barrier: Ksm reads done]
// stageK(t+1); preload V(t-1) frags to regs; [lgkm_barrier]; stageV(t) (overwrite);
// PV: acc += P(t-1).V(t-1). Tail does the final PV(31). Epilogue: lsum reduce, /l.
__global__ __launch_bounds__(512, 1) void fattn(const u8* __restrict__ QKf8,
                                                const u8* __restrict__ Vf8,
                                                u16* __restrict__ H, float scale2) {
  __shared__ u8 Ksm[65536];      // [128 j][512 B], 16B chunks, low3 ^ (j&7)  (R3)
  __shared__ u8 Vsm[65536];      // [512 c][128 B], 8 chunks, ^ (c&7)          (R3)
  __shared__ u8 Pp[2][8192];     // chunk-major [8 jc][64 i][16B]              (R5)
  __shared__ float lsum[4][64];
  int tid = threadIdx.x, lane = tid & 63, w = tid >> 6;
  int l31 = lane & 31, h = lane >> 5;
  int wi = w >> 2, wj = w & 3;
  // XCD swizzle: under round-robin dispatch xcd = lid%8; give each batch 2 XCDs
  int lid = blockIdx.x + 64 * blockIdx.z;
  int xcd = lid & 7, slot = lid >> 3;
  int bz = xcd >> 1;
  int bm = (xcd & 1) * 32 + slot;
  const u8* QKb = QKf8 + (long)bz * 4194304;
  const u8* Vb  = Vf8 + (long)bz * 2097152;

  // Q rows (bm*64 + wi*32 + l31), full c=512, resident in regs (64 VGPR)
  i32x8 qf[8];
  {
    const u8* qrow = QKb + (long)(bm * 64 + wi * 32 + l31) * 1024 + h * 32;
#pragma unroll
    for (int s = 0; s < 8; s++) {
      i32x4 lo = *(const i32x4*)(qrow + s * 64);
      i32x4 hi = *(const i32x4*)(qrow + s * 64 + 16);
      qf[s] = __builtin_shufflevector(lo, hi, 0, 1, 2, 3, 4, 5, 6, 7);
    }
  }

  auto stageK = [&](int t) {
#pragma unroll
    for (int r = 0; r < 8; r++) {
      int zz = tid + r * 512;
      int j = zz >> 5, pos = zz & 31;
      int gch = (pos & 24) | ((pos & 7) ^ (j & 7));
      async16b(QKb + (long)(t * 128 + j) * 1024 + 512 + gch * 16, &Ksm[zz * 16]);
    }
  };
  auto stageV = [&](int t) {
#pragma unroll
    for (int r = 0; r < 8; r++) {
      int zz = tid + r * 512;
      int c = zz >> 3, pos = zz & 7;
      int gch = pos ^ (c & 7);
      async16b(Vb + (long)c * 4096 + t * 128 + gch * 16, &Vsm[zz * 16]);
    }
  };

  f32x16 acc[2][2] = {};   // [i-sub][c-sub]; wave c-base = w*64
  float rsum = 0.f;
  int i = wi * 32 + l31;   // this wave's S row (lane)
  int jr = wj * 32 + l31;  // this wave's K row (lane)

  stageK(0);

  for (int t = 0; t < 32; t++) {
    vm_barrier();                 // K(t) staged; V(t-1) staged (t>0)
    // ---- phase A: S(t) = Q.K^T over c=512 (8 MFMA, regs + Ksm) ----
    f32x16 s16 = {};
#pragma unroll
    for (int s = 0; s < 8; s++) {
      int p0 = 4 * s + 2 * h;
      int pos0 = (p0 & 24) | ((p0 & 7) ^ (jr & 7));
      int pos1 = (p0 & 24) | (((p0 + 1) & 7) ^ (jr & 7));
      i32x4 lo = *(const i32x4*)&Ksm[jr * 512 + pos0 * 16];
      i32x4 hi = *(const i32x4*)&Ksm[jr * 512 + pos1 * 16];
      i32x8 bfk = __builtin_shufflevector(lo, hi, 0, 1, 2, 3, 4, 5, 6, 7);
      __builtin_amdgcn_s_setprio(1);
      s16 = __builtin_amdgcn_mfma_scale_f32_32x32x64_f8f6f4(
          bfk, qf[s], s16, 0, 0, 0, 0x7F7F7F7F, 0, 0x7F7F7F7F);
      __builtin_amdgcn_s_setprio(0);
    }
    // exp2 + rowsum + pack P(t) -> Pp[t&1] chunk-major
    {
      float pv[16];
      float rs = 0.f;
#pragma unroll
      for (int r = 0; r < 16; r++) { pv[r] = exp2f(s16[r] * scale2); rs += pv[r]; }
      rsum += rs + __shfl_xor(rs, 32, 64);
      u8* Pw = &Pp[t & 1][0];
#pragma unroll
      for (int g = 0; g < 4; g++) {
        int jc = wj * 2 + (g >> 1);
        *(unsigned*)&Pw[jc * 1024 + i * 16 + 8 * (g & 1) + 4 * h] =
            pk4_fp8(pv[4 * g], pv[4 * g + 1], pv[4 * g + 2], pv[4 * g + 3]);
      }
    }
    lgkm_barrier();               // all Ksm reads done; P(t) visible
    if (t < 31) stageK(t + 1);    // overwrite Ksm (safe)
    if (t > 0) {
      // preload V(t-1) frags to regs (R3 addressing), then overwrite Vsm
      i32x8 bfv[2][2];
#pragma unroll
      for (int kk = 0; kk < 2; kk++) {
        int g0 = kk * 4 + h * 2;
#pragma unroll
        for (int nr = 0; nr < 2; nr++) {
          int c = w * 64 + nr * 32 + l31;
          i32x4 lo = *(const i32x4*)&Vsm[c * 128 + ((g0) ^ (c & 7)) * 16];
          i32x4 hi = *(const i32x4*)&Vsm[c * 128 + ((g0 + 1) ^ (c & 7)) * 16];
          bfv[kk][nr] = __builtin_shufflevector(lo, hi, 0, 1, 2, 3, 4, 5, 6, 7);
        }
      }
      lgkm_barrier();             // V reads landed in regs
      stageV(t);                  // overwrite Vsm with V(t)
      const u8* Pr = &Pp[(t ^ 1) & 1][0];   // P(t-1)
#pragma unroll
      for (int kk = 0; kk < 2; kk++) {
        int kb = 4 * kk + 2 * h;
        i32x8 afp[2];
#pragma unroll
        for (int mr = 0; mr < 2; mr++) {
          int ii = mr * 32 + l31;
          i32x4 lo = *(const i32x4*)&Pr[kb * 1024 + ii * 16];
          i32x4 hi = *(const i32x4*)&Pr[(kb + 1) * 1024 + ii * 16];
          afp[mr] = __builtin_shufflevector(lo, hi, 0, 1, 2, 3, 4, 5, 6, 7);
        }
        __builtin_amdgcn_s_setprio(1);
#pragma unroll
        for (int mr = 0; mr < 2; mr++)
#pragma unroll
          for (int nr = 0; nr < 2; nr++)
            acc[mr][nr] = __builtin_amdgcn_mfma_scale_f32_32x32x64_f8f6f4(
                bfv[kk][nr], afp[mr], acc[mr][nr], 0, 0, 0, 0x7F7F7F7F, 0, 0x7F7F7F7F);
        __builtin_amdgcn_s_setprio(0);
      }
    } else {
      lgkm_barrier();             // uniform barrier count
      stageV(0);
    }
  }

  // ---- tail: PV for t=31 (P(31)=Pp[1], V(31) in Vsm) ----
  vm_barrier();                   // V(31) staged complete
  {
    const u8* Pr = &Pp[1][0];
#pragma unroll
    for (int kk = 0; kk < 2; kk++) {
      int kb = 4 * kk + 2 * h;
      int g0 = kk * 4 + h * 2;
      i32x8 afp[2], bfv[2];
#pragma unroll
      for (int mr = 0; mr < 2; mr++) {
        int ii = mr * 32 + l31;
        i32x4 lo = *(const i32x4*)&Pr[kb * 1024 + ii * 16];
        i32x4 hi = *(const i32x4*)&Pr[(kb + 1) * 1024 + ii * 16];
        afp[mr] = __builtin_shufflevector(lo, hi, 0, 1, 2, 3, 4, 5, 6, 7);
      }
#pragma unroll
      for (int nr = 0; nr < 2; nr++) {
        int c = w * 64 + nr * 32 + l31;
        i32x4 lo = *(const i32x4*)&Vsm[c * 128 + ((g0) ^ (c & 7)) * 16];
        i32x4 hi = *(const i32x4*)&Vsm[c * 128 + ((g0 + 1) ^ (c & 7)) * 16];
        bfv[nr] = __builtin_shufflevector(lo, hi, 0, 1, 2, 3, 4, 5, 6, 7);
      }
      __builtin_amdgcn_s_setprio(1);
#pragma unroll
      for (int mr = 0; mr < 2; mr++)
#pragma unroll
        for (int nr = 0; nr < 2; nr++)
          acc[mr][nr] = __builtin_amdgcn_mfma_scale_f32_32x32x64_f8f6f4(
              bfv[nr], afp[mr], acc[mr][nr], 0, 0, 0, 0x7F7F7F7F, 0, 0x7F7F7F7F);
      __builtin_amdgcn_s_setprio(0);
    }
  }

  // ---- epilogue: reduce rowsums across wj, divide, store H bf16 ----
  if (lane < 32) lsum[wj][wi * 32 + l31] = rsum;
  __syncthreads();
#pragma unroll
  for (int mr = 0; mr < 2; mr++) {
    int li = mr * 32 + l31;
    float lt = lsum[0][li] + lsum[1][li] + lsum[2][li] + lsum[3][li];
    float inv = 1.f / lt;
    long hrow = ((long)bz * NPOS + bm * 64 + li) * 512;
#pragma unroll
    for (int nr = 0; nr < 2; nr++) {
#pragma unroll
      for (int g = 0; g < 4; g++) {
        u16x4 o;
#pragma unroll
        for (int r = 0; r < 4; r++) o[r] = f2bf(acc[mr][nr][4 * g + r] * inv);
        *(u16x4*)&H[hrow + w * 64 + nr * 32 + 8 * g + 4 * h] = o;
      }
    }
  }
}

extern "C" void kernel_launch(void* const* d_in, const int* in_sizes, int n_in,
                              void* d_out, int out_size, void* d_ws, size_t ws_size,
                              hipStream_t stream) {
  const float* x     = (const float*)d_in[0];
  const float* gamma = (const float*)d_in[1];
  const float* beta  = (const float*)d_in[2];
  const float* wq = (const float*)d_in[3];
  const float* bq = (const float*)d_in[4];
  const float* wk = (const float*)d_in[5];
  const float* bk = (const float*)d_in[6];
  const float* wv = (const float*)d_in[7];
  const float* bv = (const float*)d_in[8];
  const float* wp = (const float*)d_in[9];
  const float* bp = (const float*)d_in[10];
  float* out = (float*)d_out;

  // workspace layout (bytes)
  char* W = (char*)d_ws;
  float* stats = (float*)(W + 0);               // 256 B
  u16* xnb  = (u16*)(W + 65792);                // 16,777,216 bf16 [b,c,p] residual
  u16* xnT  = (u16*)(W + 16843008);             // 16,777,216 bf16 [b,p,c]
  u16* wqkb = (u16*)(W + 33620224);             // 1,048,576  bf16 [1024(cq;ck)][512]
  u16* wvb  = (u16*)(W + 34668800);             // 524,288    bf16 [512][512]
  u16* wpb  = (u16*)(W + 35193088);             // 524,288    bf16 [512][512]
  u8*  QKf8 = (u8*)(W + 37290240);              // 16,777,216 fp8 [b,p,1024] (Q|K)
  u8*  Vf8  = (u8*)(W + 54067456);              // 8,388,608  fp8 [b,c,p]
  u16* Hws  = (u16*)(W + 62456064);             // 16,777,216 bf16 [b,i,512]
  (void)in_sizes; (void)n_in; (void)out_size; (void)ws_size;

  hipMemsetAsync(W, 0, 256, stream);   // stats
  gn_partial<<<256, 256, 0, stream>>>(x, stats);
  norm_trans<<<dim3(128, 16, 4), 256, 0, stream>>>(x, stats, gamma, beta, xnb, xnT);
  cvt4<<<dim3(1024, 4), 256, 0, stream>>>(wq, wk, wv, wp, wqkb, wqkb + 262144, wvb, wpb);

  const long NC = (long)NPOS * CDIM;    // 2,097,152
  const long CN = (long)CDIM * NPOS;
  const float scale = 0.044194173824159216f;        // 1/sqrt(512)
  const float scale2 = scale * 1.4426950408889634f; // 1/sqrt(512) * log2(e)

  // QKf8[b*p, 0:512]=Q, [512:1024]=K (fp8): A=xnT (M=16384), B=wqkb (N=1024), K=512
  gemm_bt<0, 128><<<dim3(8, 128, 1), 256, 0, stream>>>(xnT, wqkb, QKf8, bq, bk, nullptr,
      1024, CDIM, CDIM, CDIM, 0, 0, 0, 0);
  // V fp8 [b][c, p] = wv . xnT_b^T + bv  (M=512, N=4096, K=512)
  gemm_bt<5, 128><<<dim3(32, 4, 4), 256, 0, stream>>>(wvb, xnT, Vf8, bv, nullptr, nullptr,
      NPOS, CDIM, CDIM, CDIM, 0, NC, CN, 0);
  // fused attention: H[b,i,512] = softmax(Q.K^T/sqrt(c)) . V
  fattn<<<dim3(64, 1, NBATCH), 512, 0, stream>>>(QKf8, Vf8, Hws, scale2);
  // out[b][c, p] = wp . H_b^T + bp + xnb  (M=512, N=4096, K=512)
  gemm_bt<6, 128><<<dim3(32, 4, 4), 256, 0, stream>>>(wpb, Hws, (void*)out, bp, nullptr, xnb,
      NPOS, CDIM, CDIM, CDIM, 0, (long)NPOS * CDIM, CN, CN);
}

// Round 7
// 287.913 us; speedup vs baseline: 1.3276x; 1.1332x over previous
//
#include <hip/hip_runtime.h>
#include <hip/hip_bf16.h>

// AttnBlock: x[4,512,64,64] fp32. GroupNorm(8) -> qkv 1x1conv -> attn -> proj -> +xn
// Q,K,V,P fp8 e4m3. R12 = composition of verified wins:
//  - fattn loop = R3 structure (best measured): 512thr/8 waves, i-tile 64,
//    j-step 128, 32 steps, 2 full drains/step, stageV at step start (hidden
//    under S-phase), stageK mid-step (hidden under PV phase).
//  - XCD swizzle (R6-verified, FETCH 74->30 MB): lid%8=XCD, 2 XCDs per batch
//    so each XCD L2 caches one batch's K+V (4MB); staging becomes L2-hits.
//  - P chunk-major [8 jc][64 i][16B] (R5/R6-verified): conflict-free P reads.
//  - K/V row-major+XOR layouts (global side of global_load_lds must stay
//    coalesced - R5 lesson).

typedef unsigned short u16;
typedef unsigned char u8;
typedef __bf16 bf16x8 __attribute__((ext_vector_type(8)));
typedef float f32x4 __attribute__((ext_vector_type(4)));
typedef float f32x16 __attribute__((ext_vector_type(16)));
typedef int i32x4 __attribute__((ext_vector_type(4)));
typedef int i32x8 __attribute__((ext_vector_type(8)));
typedef unsigned short u16x4 __attribute__((ext_vector_type(4)));

#define CDIM 512
#define NPOS 4096
#define NBATCH 4

__device__ __forceinline__ u16 f2bf(float x) {
  union { float f; unsigned u; } c; c.f = x;
  unsigned u = c.u;
  u += 0x7fffu + ((u >> 16) & 1u);   // round-to-nearest-even
  return (u16)(u >> 16);
}
__device__ __forceinline__ float bf2f(u16 h) {
  union { unsigned u; float f; } c; c.u = ((unsigned)h) << 16;
  return c.f;
}
// pack 4 floats -> 4 fp8 e4m3 bytes
__device__ __forceinline__ unsigned pk4_fp8(float a, float b, float c, float d) {
  unsigned v = __builtin_amdgcn_cvt_pk_fp8_f32(a, b, 0, false);
  v = __builtin_amdgcn_cvt_pk_fp8_f32(c, d, v, true);
  return v;
}

__device__ __forceinline__ void async16(const u16* g, u16* l) {
  __builtin_amdgcn_global_load_lds(
      (const __attribute__((address_space(1))) unsigned int*)g,
      (__attribute__((address_space(3))) unsigned int*)l, 16, 0, 0);
}
__device__ __forceinline__ void async16b(const u8* g, u8* l) {
  __builtin_amdgcn_global_load_lds(
      (const __attribute__((address_space(1))) unsigned int*)g,
      (__attribute__((address_space(3))) unsigned int*)l, 16, 0, 0);
}

__device__ __forceinline__ void drain_barrier() {
  asm volatile("s_waitcnt vmcnt(0)" ::: "memory");
  __builtin_amdgcn_s_barrier();
}

__device__ __forceinline__ float wred_sum(float v) {
#pragma unroll
  for (int o = 32; o > 0; o >>= 1) v += __shfl_xor(v, o, 64);
  return v;
}

// ---------------- GroupNorm stats: 32 (b,g) groups x 8 slices ----------------
__global__ __launch_bounds__(256) void gn_partial(const float* __restrict__ x,
                                                  float* __restrict__ stats) {
  int gidx = blockIdx.x >> 3;
  int slice = blockIdx.x & 7;
  const float4* src = (const float4*)x + (long)gidx * 65536 + (long)slice * 8192;
  float s = 0.f, ss = 0.f;
  for (int i = threadIdx.x; i < 8192; i += 256) {
    float4 v = src[i];
    s  += v.x + v.y + v.z + v.w;
    ss += v.x * v.x + v.y * v.y + v.z * v.z + v.w * v.w;
  }
  s = wred_sum(s); ss = wred_sum(ss);
  __shared__ float r1[4], r2[4];
  int lane = threadIdx.x & 63, wave = threadIdx.x >> 6;
  if (lane == 0) { r1[wave] = s; r2[wave] = ss; }
  __syncthreads();
  if (threadIdx.x == 0) {
    atomicAdd(&stats[gidx * 2 + 0], r1[0] + r1[1] + r1[2] + r1[3]);
    atomicAdd(&stats[gidx * 2 + 1], r2[0] + r2[1] + r2[2] + r2[3]);
  }
}

// ------- normalize + write xnb bf16 [b,c,p] (residual) and xnT bf16 [b,p,c] -------
__global__ __launch_bounds__(256) void norm_trans(const float* __restrict__ x,
                                                  const float* __restrict__ stats,
                                                  const float* __restrict__ gamma,
                                                  const float* __restrict__ beta,
                                                  u16* __restrict__ xnb,
                                                  u16* __restrict__ xnT) {
  __shared__ float tile[32][33];
  int b = blockIdx.z, c0 = blockIdx.y * 32, p0 = blockIdx.x * 32;
  int g = (b << 3) + (c0 >> 6);
  float cnt = 1.f / 262144.f;
  float mu = stats[g * 2 + 0] * cnt;
  float ms = stats[g * 2 + 1] * cnt;
  float rstd = rsqrtf(ms - mu * mu + 1e-5f);
  int tp = threadIdx.x & 31, tc = threadIdx.x >> 5;
#pragma unroll
  for (int r = 0; r < 4; r++) {
    int cl = tc + r * 8;
    int c = c0 + cl;
    long idx = ((long)(b * CDIM + c)) * NPOS + p0 + tp;
    float v = (x[idx] - mu) * rstd * gamma[c] + beta[c];
    xnb[idx] = f2bf(v);
    tile[cl][tp] = v;
  }
  __syncthreads();
#pragma unroll
  for (int r = 0; r < 4; r++) {
    int pl = tc + r * 8, cl = tp;
    xnT[((long)(b * NPOS + p0 + pl)) * CDIM + c0 + cl] = f2bf(tile[cl][pl]);
  }
}

// ------- fp32 -> bf16 weight convert (wq, wk, wv, wp all [512][512]) -------
__global__ __launch_bounds__(256) void cvt4(const float* __restrict__ a, const float* __restrict__ b,
                                            const float* __restrict__ c, const float* __restrict__ d,
                                            u16* __restrict__ oa, u16* __restrict__ ob,
                                            u16* __restrict__ oc, u16* __restrict__ od) {
  int i = blockIdx.x * 256 + threadIdx.x;
  const float* src; u16* dst;
  switch (blockIdx.y) {
    case 0: src = a; dst = oa; break;
    case 1: src = b; dst = ob; break;
    case 2: src = c; dst = oc; break;
    default: src = d; dst = od; break;
  }
  dst[i] = f2bf(src[i]);
}

// ---------------- gemm_bt: C[m,n] = sum_k A[m,k]*B[n,k]  (both K-contig, bf16) ----------------
// 128(M) x BN tile, BK=64, BN/64*2 waves (wave tile 64x64), XOR-swizzled LDS, dbuf.
// MFMA operands SWAPPED: mfma(bfr, af, acc) -> C/D lane dim = m, reg dim = n.
// MODE 0: fp8 out, + bias[n] (bias|bias1 split at n=512)    (fused QK -> fp8)
// MODE 5: fp8 out, + bias[m]                                (V fp8)
// MODE 6: f32  out = acc + bias[m] + bf16 resid             (proj + residual)
template <int MODE, int BN>
__global__ __launch_bounds__(BN * 2, 2) void gemm_bt(
    const u16* __restrict__ A, const u16* __restrict__ B,
    void* __restrict__ Cp, const float* __restrict__ bias,
    const float* __restrict__ bias1, const u16* __restrict__ residb,
    int N, int K, int lda, int ldb,
    long sA, long sB, long sC, long sR) {
  __shared__ u16 Asm[2][128 * 64];
  __shared__ u16 Bsm[2][BN * 64];
  constexpr int NT = BN * 2;       // threads
  constexpr int STEP = NT / 8;     // staging rows per round
  int bz = blockIdx.z;
  A += (long)bz * sA;
  B += (long)bz * sB;
  int bm = blockIdx.y, bn = blockIdx.x;
  int tid = threadIdx.x;
  int lane = tid & 63, wave = tid >> 6;
  int wm = (wave & 1) * 64, wn = (wave >> 1) * 64;

  int row0 = tid >> 3;             // 0..STEP-1
  int ko = (tid & 7) * 8;
  int kos = ko ^ ((row0 & 7) * 8); // STEP multiple of 8 -> row&7 invariant
  f32x4 acc[4][4] = {};
  int row16 = lane & 15;
  int kq = (lane >> 4) * 8;

  auto stage = [&](int buf, int k0) {
#pragma unroll
    for (int r = 0; r < 128 / STEP; r++) {
      int row = row0 + r * STEP;
      async16(A + (long)(bm * 128 + row) * lda + k0 + kos, &Asm[buf][row * 64 + ko]);
    }
#pragma unroll
    for (int r = 0; r < BN / STEP; r++) {
      int row = row0 + r * STEP;
      async16(B + (long)(bn * BN + row) * ldb + k0 + kos, &Bsm[buf][row * 64 + ko]);
    }
  };

  stage(0, 0);
  drain_barrier();
  int cur = 0;
  for (int k0 = 0; k0 < K; k0 += 64) {
    if (k0 + 64 < K) stage(cur ^ 1, k0 + 64);   // prefetch next tile
#pragma unroll
    for (int s2 = 0; s2 < 2; s2++) {
      bf16x8 af[4], bfr[4];
#pragma unroll
      for (int i = 0; i < 4; i++) {
        int row = wm + i * 16 + row16;
        af[i] = *(const bf16x8*)&Asm[cur][row * 64 + ((s2 * 32 + kq) ^ ((row & 7) * 8))];
      }
#pragma unroll
      for (int j = 0; j < 4; j++) {
        int row = wn + j * 16 + row16;
        bfr[j] = *(const bf16x8*)&Bsm[cur][row * 64 + ((s2 * 32 + kq) ^ ((row & 7) * 8))];
      }
      __builtin_amdgcn_s_setprio(1);
#pragma unroll
      for (int i = 0; i < 4; i++)
#pragma unroll
        for (int j = 0; j < 4; j++)
          acc[i][j] = __builtin_amdgcn_mfma_f32_16x16x32_bf16(bfr[j], af[i], acc[i][j], 0, 0, 0);
      __builtin_amdgcn_s_setprio(0);
    }
    drain_barrier();
    cur ^= 1;
  }

  // epilogue (swapped layout): m = lane&15 within tile, n = (lane>>4)*4 + reg
  int mcol = lane & 15, rb = (lane >> 4) * 4;
  long zC = (long)bz * sC;
#pragma unroll
  for (int i = 0; i < 4; i++) {
    int gm = bm * 128 + wm + i * 16 + mcol;
    float bm_add = 0.f;
    if constexpr (MODE == 5 || MODE == 6) bm_add = bias[gm];
#pragma unroll
    for (int j = 0; j < 4; j++) {
      int gn0 = bn * BN + wn + j * 16 + rb;
      long off = zC + (long)gm * N + gn0;
      float v[4];
#pragma unroll
      for (int r = 0; r < 4; r++) v[r] = acc[i][j][r];
      if constexpr (MODE == 0) {
        const float* bb = (gn0 < 512) ? (bias + gn0) : (bias1 + (gn0 - 512));
#pragma unroll
        for (int r = 0; r < 4; r++) v[r] += bb[r];
        *(unsigned*)&((u8*)Cp)[off] = pk4_fp8(v[0], v[1], v[2], v[3]);
      }
      if constexpr (MODE == 5) {
#pragma unroll
        for (int r = 0; r < 4; r++) v[r] += bm_add;
        *(unsigned*)&((u8*)Cp)[off] = pk4_fp8(v[0], v[1], v[2], v[3]);
      }
      if constexpr (MODE == 6) {
        u16x4 rv = *(const u16x4*)&residb[(long)bz * sR + (long)gm * N + gn0];
        f32x4 o;
#pragma unroll
        for (int r = 0; r < 4; r++) o[r] = v[r] + bm_add + bf2f(rv[r]);
        *(f32x4*)&((float*)Cp)[off] = o;
      }
    }
  }
}

// ---------------- fattn: fused S=exp(QK^T*scale) and H=(S.V)/rowsum ----------------
// 256 blocks (XCD-swizzled: 2 XCDs per batch), 512 thr (8 waves: wi=w>>2, wj=w&3).
// i-tile 64, j-step 128, 32 steps. MX-fp8 MFMA 32x32x64, swapped operands
// (D lane=m(l31), reg n=(r&3)+8*(r>>2)+4*h; A/B frag: lane=row, k-bytes h*32..+31).
// Per step (R3 schedule): [sync A: K(t) staged, V/P reads of t-1 done] stageV(t);
// S=Q.K(t) (8 MFMA); exp2 -> P chunk-major LDS + rowsum; [sync B: V(t) staged,
// P visible] stageK(t+1); acc += P.V^T (8 MFMA). Epilogue: lsum reduce, /l.
__global__ __launch_bounds__(512, 1) void fattn(const u8* __restrict__ QKf8,
                                                const u8* __restrict__ Vf8,
                                                u16* __restrict__ H, float scale2) {
  __shared__ u8 Ksm[65536];      // [128 j][512 B], 16B chunks, low3 ^ (j&7)
  __shared__ u8 Vsm[65536];      // [512 c][128 B], 8 chunks, ^ (c&7)
  __shared__ u8 Pp[8192];        // chunk-major [8 jc][64 i][16B]
  __shared__ float lsum[4][64];
  int tid = threadIdx.x, lane = tid & 63, w = tid >> 6;
  int l31 = lane & 31, h = lane >> 5;
  int wi = w >> 2, wj = w & 3;
  // XCD swizzle (R6-verified): under round-robin dispatch xcd = lid%8;
  // 2 XCDs per batch -> each XCD's 4MB L2 holds one batch's K+V (3MB... fits).
  int lid = blockIdx.x + 64 * blockIdx.z;
  int xcd = lid & 7, slot = lid >> 3;
  int bz = xcd >> 1;
  int bm = (xcd & 1) * 32 + slot;
  const u8* QKb = QKf8 + (long)bz * 4194304;
  const u8* Vb  = Vf8 + (long)bz * 2097152;

  // Q rows (bm*64 + wi*32 + l31), full c=512, resident in regs (64 VGPR)
  i32x8 qf[8];
  {
    const u8* qrow = QKb + (long)(bm * 64 + wi * 32 + l31) * 1024 + h * 32;
#pragma unroll
    for (int s = 0; s < 8; s++) {
      i32x4 lo = *(const i32x4*)(qrow + s * 64);
      i32x4 hi = *(const i32x4*)(qrow + s * 64 + 16);
      qf[s] = __builtin_shufflevector(lo, hi, 0, 1, 2, 3, 4, 5, 6, 7);
    }
  }

  auto stageK = [&](int t) {
#pragma unroll
    for (int r = 0; r < 8; r++) {
      int zz = tid + r * 512;
      int j = zz >> 5, pos = zz & 31;
      int gch = (pos & 24) | ((pos & 7) ^ (j & 7));
      async16b(QKb + (long)(t * 128 + j) * 1024 + 512 + gch * 16, &Ksm[zz * 16]);
    }
  };
  auto stageV = [&](int t) {
#pragma unroll
    for (int r = 0; r < 8; r++) {
      int zz = tid + r * 512;
      int c = zz >> 3, pos = zz & 7;
      int gch = pos ^ (c & 7);
      async16b(Vb + (long)c * 4096 + t * 128 + gch * 16, &Vsm[zz * 16]);
    }
  };

  f32x16 acc[2][2] = {};   // [i-sub][c-sub]; wave c-base = w*64
  float rsum = 0.f;
  int i = wi * 32 + l31;   // this wave's S row (lane)
  int jr = wj * 32 + l31;  // this wave's K row (lane)

  stageK(0);

  for (int t = 0; t < 32; t++) {
    __syncthreads();              // A: K(t) staged+drained; Vsm/Pp reads of t-1 done
    stageV(t);
    // ---- phase 1: S = Q.K^T over c=512 (8 MFMA, regs + Ksm) ----
    f32x16 s16 = {};
#pragma unroll
    for (int s = 0; s < 8; s++) {
      int p0 = 4 * s + 2 * h;
      int pos0 = (p0 & 24) | ((p0 & 7) ^ (jr & 7));
      int pos1 = (p0 & 24) | (((p0 + 1) & 7) ^ (jr & 7));
      i32x4 lo = *(const i32x4*)&Ksm[jr * 512 + pos0 * 16];
      i32x4 hi = *(const i32x4*)&Ksm[jr * 512 + pos1 * 16];
      i32x8 bfk = __builtin_shufflevector(lo, hi, 0, 1, 2, 3, 4, 5, 6, 7);
      __builtin_amdgcn_s_setprio(1);
      s16 = __builtin_amdgcn_mfma_scale_f32_32x32x64_f8f6f4(
          bfk, qf[s], s16, 0, 0, 0, 0x7F7F7F7F, 0, 0x7F7F7F7F);
      __builtin_amdgcn_s_setprio(0);
    }
    // exp2 + rowsum + pack P -> LDS chunk-major (reg r: j = wj*32+(r&3)+8*(r>>2)+4h)
    {
      float pv[16];
      float rs = 0.f;
#pragma unroll
      for (int r = 0; r < 16; r++) { pv[r] = exp2f(s16[r] * scale2); rs += pv[r]; }
      rsum += rs + __shfl_xor(rs, 32, 64);
#pragma unroll
      for (int g = 0; g < 4; g++) {
        int jc = wj * 2 + (g >> 1);
        *(unsigned*)&Pp[jc * 1024 + i * 16 + 8 * (g & 1) + 4 * h] =
            pk4_fp8(pv[4 * g], pv[4 * g + 1], pv[4 * g + 2], pv[4 * g + 3]);
      }
    }
    __syncthreads();              // B: V(t) staged+drained; Pp writes visible
    if (t < 31) stageK(t + 1);
    // ---- phase 2: acc += P.V^T over local j=128 (2 MFMA k-steps) ----
#pragma unroll
    for (int kk = 0; kk < 2; kk++) {
      int kb = 4 * kk + 2 * h;
      int g0 = kk * 4 + h * 2;
      i32x8 afp[2], bfv[2];
#pragma unroll
      for (int mr = 0; mr < 2; mr++) {
        int ii = mr * 32 + l31;
        i32x4 lo = *(const i32x4*)&Pp[kb * 1024 + ii * 16];
        i32x4 hi = *(const i32x4*)&Pp[(kb + 1) * 1024 + ii * 16];
        afp[mr] = __builtin_shufflevector(lo, hi, 0, 1, 2, 3, 4, 5, 6, 7);
      }
#pragma unroll
      for (int nr = 0; nr < 2; nr++) {
        int c = w * 64 + nr * 32 + l31;
        i32x4 lo = *(const i32x4*)&Vsm[c * 128 + ((g0) ^ (c & 7)) * 16];
        i32x4 hi = *(const i32x4*)&Vsm[c * 128 + ((g0 + 1) ^ (c & 7)) * 16];
        bfv[nr] = __builtin_shufflevector(lo, hi, 0, 1, 2, 3, 4, 5, 6, 7);
      }
      __builtin_amdgcn_s_setprio(1);
#pragma unroll
      for (int mr = 0; mr < 2; mr++)
#pragma unroll
        for (int nr = 0; nr < 2; nr++)
          acc[mr][nr] = __builtin_amdgcn_mfma_scale_f32_32x32x64_f8f6f4(
              bfv[nr], afp[mr], acc[mr][nr], 0, 0, 0, 0x7F7F7F7F, 0, 0x7F7F7F7F);
      __builtin_amdgcn_s_setprio(0);
    }
  }

  // ---- epilogue: reduce rowsums across wj, divide, store H bf16 ----
  if (lane < 32) lsum[wj][wi * 32 + l31] = rsum;
  __syncthreads();
#pragma unroll
  for (int mr = 0; mr < 2; mr++) {
    int li = mr * 32 + l31;
    float lt = lsum[0][li] + lsum[1][li] + lsum[2][li] + lsum[3][li];
    float inv = 1.f / lt;
    long hrow = ((long)bz * NPOS + bm * 64 + li) * 512;
#pragma unroll
    for (int nr = 0; nr < 2; nr++) {
#pragma unroll
      for (int g = 0; g < 4; g++) {
        u16x4 o;
#pragma unroll
        for (int r = 0; r < 4; r++) o[r] = f2bf(acc[mr][nr][4 * g + r] * inv);
        *(u16x4*)&H[hrow + w * 64 + nr * 32 + 8 * g + 4 * h] = o;
      }
    }
  }
}

extern "C" void kernel_launch(void* const* d_in, const int* in_sizes, int n_in,
                              void* d_out, int out_size, void* d_ws, size_t ws_size,
                              hipStream_t stream) {
  const float* x     = (const float*)d_in[0];
  const float* gamma = (const float*)d_in[1];
  const float* beta  = (const float*)d_in[2];
  const float* wq = (const float*)d_in[3];
  const float* bq = (const float*)d_in[4];
  const float* wk = (const float*)d_in[5];
  const float* bk = (const float*)d_in[6];
  const float* wv = (const float*)d_in[7];
  const float* bv = (const float*)d_in[8];
  const float* wp = (const float*)d_in[9];
  const float* bp = (const float*)d_in[10];
  float* out = (float*)d_out;

  // workspace layout (bytes)
  char* W = (char*)d_ws;
  float* stats = (float*)(W + 0);               // 256 B
  u16* xnb  = (u16*)(W + 65792);                // 16,777,216 bf16 [b,c,p] residual
  u16* xnT  = (u16*)(W + 16843008);             // 16,777,216 bf16 [b,p,c]
  u16* wqkb = (u16*)(W + 33620224);             // 1,048,576  bf16 [1024(cq;ck)][512]
  u16* wvb  = (u16*)(W + 34668800);             // 524,288    bf16 [512][512]
  u16* wpb  = (u16*)(W + 35193088);             // 524,288    bf16 [512][512]
  u8*  QKf8 = (u8*)(W + 37290240);              // 16,777,216 fp8 [b,p,1024] (Q|K)
  u8*  Vf8  = (u8*)(W + 54067456);              // 8,388,608  fp8 [b,c,p]
  u16* Hws  = (u16*)(W + 62456064);             // 16,777,216 bf16 [b,i,512]
  (void)in_sizes; (void)n_in; (void)out_size; (void)ws_size;

  hipMemsetAsync(W, 0, 256, stream);   // stats
  gn_partial<<<256, 256, 0, stream>>>(x, stats);
  norm_trans<<<dim3(128, 16, 4), 256, 0, stream>>>(x, stats, gamma, beta, xnb, xnT);
  cvt4<<<dim3(1024, 4), 256, 0, stream>>>(wq, wk, wv, wp, wqkb, wqkb + 262144, wvb, wpb);

  const long NC = (long)NPOS * CDIM;    // 2,097,152
  const long CN = (long)CDIM * NPOS;
  const float scale = 0.044194173824159216f;        // 1/sqrt(512)
  const float scale2 = scale * 1.4426950408889634f; // 1/sqrt(512) * log2(e)

  // QKf8[b*p, 0:512]=Q, [512:1024]=K (fp8): A=xnT (M=16384), B=wqkb (N=1024), K=512
  gemm_bt<0, 128><<<dim3(8, 128, 1), 256, 0, stream>>>(xnT, wqkb, QKf8, bq, bk, nullptr,
      1024, CDIM, CDIM, CDIM, 0, 0, 0, 0);
  // V fp8 [b][c, p] = wv . xnT_b^T + bv  (M=512, N=4096, K=512)
  gemm_bt<5, 128><<<dim3(32, 4, 4), 256, 0, stream>>>(wvb, xnT, Vf8, bv, nullptr, nullptr,
      NPOS, CDIM, CDIM, CDIM, 0, NC, CN, 0);
  // fused attention: H[b,i,512] = softmax(Q.K^T/sqrt(c)) . V
  fattn<<<dim3(64, 1, NBATCH), 512, 0, stream>>>(QKf8, Vf8, Hws, scale2);
  // out[b][c, p] = wp . H_b^T + bp + xnb  (M=512, N=4096, K=512)
  gemm_bt<6, 128><<<dim3(32, 4, 4), 256, 0, stream>>>(wpb, Hws, (void*)out, bp, nullptr, xnb,
      NPOS, CDIM, CDIM, CDIM, 0, (long)NPOS * CDIM, CN, CN);
}